// Round 26
// baseline (48.049 us; speedup 1.0000x reference)
//
#include <hip/hip_runtime.h>
#include <math.h>

// Problem constants (match reference)
constexpr int B = 8, S = 128, T = 4096;
constexpr int NPIX = 256 * 256;          // NX*NY
constexpr float RVS = 1.0f / 1550.0f;    // compile-time correctly-rounded f32
constexpr float RDT = 1.0e7f;            // fl32(1/fl32(1e-7)) == 1e7 (exact)
constexpr int NCHUNK = 8;                // sensor chunks == XCD count
constexpr int SCHUNK = S / NCHUNK;       // 16
constexpr int GROUP  = 4;                // sensors staged per barrier pair
constexpr int WROWS  = 160;              // staged t-rows: span<=138 (+3 align) <160
constexpr size_t PART_BYTES = (size_t)NPIX * B * sizeof(float);       // 2 MB
constexpr size_t MM_OFF     = NCHUNK * PART_BYTES;                    // 16 MB
constexpr size_t WS_NEED    = MM_OFF + 256;

// Verified t-chain (round 11, absmax 0.0039): XLA f32 with x/const -> x*(1/const).
// Monotone non-decreasing in |dx|,|dy| (incl. rounding) -> interval endpoints
// give exact per-tile t-bounds.
__device__ __forceinline__ int tof_index(int dxi, int dyi) {
    float ax = (float)dxi * 1e-3f;
    float ay = (float)dyi * 1e-3f;
    float px = ax * ax;
    float py = ay * ay;
    asm volatile("" : "+v"(px));         // pin rounded squares: forbid FMA
    asm volatile("" : "+v"(py));
    float d2  = px + py;
    float dis = __fsqrt_rn(d2);
    float q1  = __fmul_rn(dis, RVS);
    asm volatile("" : "+v"(q1));
    float tf  = __fmul_rn(q1, RDT);
    return (int)tf;                      // t_max == 2326; 2326+159 < 4096 (in-bounds)
}

// Orderable uint mapping for float min/max atomics (monotonic, bijective).
__device__ __forceinline__ unsigned fkey(float f) {
    unsigned u = __float_as_uint(f);
    return ((int)u < 0) ? ~u : (u | 0x80000000u);
}
__device__ __forceinline__ float funkey(unsigned k) {
    return __uint_as_float(((int)k < 0) ? (k ^ 0x80000000u) : ~k);
}

// ---------- fast path (3 kernels) ----------

// Delay-and-sum with GROUPed LDS window staging + PRECOMPUTED t offsets.
// Rounds 21-25 showed occupancy tier, barrier count, and double-buffering
// are all neutral-to-negative: the stall is the ~44-cycle serial tof_index
// chain gating each sensor's LDS reads inside every barrier phase. Fix:
// hoist all 16 t-computations (independent -> pipelined) into registers
// BEFORE the loop; gather phases then issue LDS reads immediately.
// (256,4): 64-VGPR budget for tpre[16]+acc[8] (round-19 spill lesson).
__global__ __launch_bounds__(256, 4) void das_accumw(const float* __restrict__ data,
                                                     const int* __restrict__ sxy,
                                                     float* __restrict__ part,
                                                     unsigned* __restrict__ mm) {
    __shared__ float win[GROUP * B * WROWS];      // 20480 B
    unsigned bid = blockIdx.x;
    int tid = threadIdx.x;
    if (bid == 0 && tid < 16) mm[tid] = (tid < 8) ? 0xFFFFFFFFu : 0u;

    int chunk = bid & 7;                          // -> XCD chunk
    int tile  = bid >> 3;                         // 0..255 (16x16 tile grid)
    int tx0 = ((tile >> 4) << 4), ty0 = ((tile & 15) << 4);
    int l = tid & 63, w = tid >> 6;
    int ix = tx0 + ((w >> 1) << 3) + (l >> 3);
    int iy = ty0 + ((w & 1) << 3) + (l & 7);
    int p  = (ix << 8) + iy;

    int s0 = chunk * SCHUNK;

    // Hoisted: window-relative t for all 16 sensors (16 independent chains).
    int tpre[SCHUNK];
#pragma unroll
    for (int k = 0; k < SCHUNK; ++k) {
        int s = s0 + k;
        int x = sxy[2 * s], y = sxy[2 * s + 1];   // uniform s_load
        int dxm = max(0, max(tx0 - x, x - (tx0 + 15)));
        int dym = max(0, max(ty0 - y, y - (ty0 + 15)));
        int tbase = tof_index(dxm, dym) & ~3;     // float4-aligned window base
        tpre[k] = tof_index(abs(x - ix), abs(y - iy)) - tbase;  // [0,160)
    }

    float acc[B];
#pragma unroll
    for (int b = 0; b < B; ++b) acc[b] = 0.0f;

#pragma unroll                                    // 4 iters: tpre idx static
    for (int k = 0; k < SCHUNK; k += GROUP) {
        __syncthreads();                          // win free of prev readers
#pragma unroll
        for (int g = 0; g < GROUP; ++g) {
            int s = s0 + k + g;
            int x = sxy[2 * s], y = sxy[2 * s + 1];
            int dxm = max(0, max(tx0 - x, x - (tx0 + 15)));
            int dym = max(0, max(ty0 - y, y - (ty0 + 15)));
            int tbase = tof_index(dxm, dym) & ~3;
            const float* srow = data + (size_t)s * T + tbase;
            int o4 = tid;                         // 0..255
            int bb = o4 / 40, t4 = o4 - bb * 40;  // const divisor -> magic mul
            *(float4*)&win[(g * B + bb) * WROWS + t4 * 4] =
                *(const float4*)(srow + (size_t)bb * (S * T) + t4 * 4);
            o4 = tid + 256;                       // 256..319 (64 active)
            if (o4 < (B * WROWS) / 4) {
                bb = o4 / 40; t4 = o4 - bb * 40;
                *(float4*)&win[(g * B + bb) * WROWS + t4 * 4] =
                    *(const float4*)(srow + (size_t)bb * (S * T) + t4 * 4);
            }
        }
        __syncthreads();                          // windows visible

#pragma unroll
        for (int g = 0; g < GROUP; ++g) {         // LDS reads gated only by tpre
            int t = tpre[k + g];                  // static index (full unroll)
#pragma unroll
            for (int bb = 0; bb < B; ++bb)
                acc[bb] += win[(g * B + bb) * WROWS + t];  // s-ascending order
        }
    }

    float* dst = part + (size_t)chunk * NPIX * B;
#pragma unroll
    for (int b = 0; b < B; ++b)
        __builtin_nontemporal_store(acc[b], dst + b * NPIX + p);
}

// Combine the 8 chunk partials into out AND per-batch min/max (atomic keys).
// 4 pixels/thread; each block spans 1024 consecutive pixels of ONE batch.
__global__ __launch_bounds__(256) void das_combine(const float* __restrict__ part,
                                                   float* __restrict__ out,
                                                   unsigned* __restrict__ mm) {
    size_t i4 = ((size_t)blockIdx.x * 256 + threadIdx.x) * 4;
    int b = (int)(i4 >> 16);
    float4 v = make_float4(0.f, 0.f, 0.f, 0.f);
#pragma unroll
    for (int c = 0; c < NCHUNK; ++c) {
        const float* q = part + (size_t)c * NPIX * B + i4;
        v.x += __builtin_nontemporal_load(q);
        v.y += __builtin_nontemporal_load(q + 1);
        v.z += __builtin_nontemporal_load(q + 2);
        v.w += __builtin_nontemporal_load(q + 3);
    }
    *(float4*)(out + i4) = v;

    float mn = fminf(fminf(v.x, v.y), fminf(v.z, v.w));
    float mx = fmaxf(fmaxf(v.x, v.y), fmaxf(v.z, v.w));
    for (int off = 32; off; off >>= 1) {
        mn = fminf(mn, __shfl_down(mn, off));
        mx = fmaxf(mx, __shfl_down(mx, off));
    }
    __shared__ float smn[4], smx[4];
    int w = threadIdx.x >> 6;
    if ((threadIdx.x & 63) == 0) { smn[w] = mn; smx[w] = mx; }
    __syncthreads();
    if (threadIdx.x == 0) {
        mn = fminf(fminf(smn[0], smn[1]), fminf(smn[2], smn[3]));
        mx = fmaxf(fmaxf(smx[0], smx[1]), fmaxf(smx[2], smx[3]));
        atomicMin(&mm[b], fkey(mn));
        atomicMax(&mm[8 + b], fkey(mx));
    }
}

// Per-batch min-max normalization, 4 pixels/thread, in place.
__global__ __launch_bounds__(256) void das_norm3(float* __restrict__ out,
                                                 const unsigned* __restrict__ mm) {
    size_t i4 = ((size_t)blockIdx.x * 256 + threadIdx.x) * 4;
    int b = (int)(i4 >> 16);
    float mn = funkey(mm[b]);
    float rs = __fsub_rn(funkey(mm[8 + b]), mn);
    float4 v = *(float4*)(out + i4);
    v.x = __fdiv_rn(__fsub_rn(v.x, mn), rs);
    v.y = __fdiv_rn(__fsub_rn(v.y, mn), rs);
    v.z = __fdiv_rn(__fsub_rn(v.z, mn), rs);
    v.w = __fdiv_rn(__fsub_rn(v.w, mn), rs);
    *(float4*)(out + i4) = v;
}

// ---------- fallback path (round-12, proven, needs 128KB ws) ----------

__global__ __launch_bounds__(256) void build_tab(unsigned short* __restrict__ tab) {
    int i = blockIdx.x * 256 + threadIdx.x;
    tab[i] = (unsigned short)tof_index(i >> 8, i & 255);
}

__global__ __launch_bounds__(256) void das_accum(const float* __restrict__ data,
                                                 const int* __restrict__ sxy,
                                                 const unsigned short* __restrict__ tab,
                                                 float* __restrict__ out) {
    __shared__ int sx[S], sy[S];
    int tid = threadIdx.x;
    if (tid < S) { sx[tid] = sxy[2 * tid]; sy[tid] = sxy[2 * tid + 1]; }
    __syncthreads();
    int b = blockIdx.x >> 8, ix = blockIdx.x & 255, iy = tid;
    int p = (ix << 8) + iy;
    const float* dbase = data + b * (S * T);
    double acc = 0.0;
#pragma unroll 8
    for (int s = 0; s < S; ++s) {
        int t = (int)tab[(abs(sx[s] - ix) << 8) + abs(sy[s] - iy)];
        acc += (double)dbase[s * T + t];
    }
    out[b * NPIX + p] = (float)acc;
}

__global__ __launch_bounds__(1024) void das_minmax(const float* __restrict__ img,
                                                   float* __restrict__ mmf) {
    int b = blockIdx.x;
    const float* p = img + b * NPIX;
    float mn = 3.0e38f, mx = -3.0e38f;
    for (int i = threadIdx.x; i < NPIX; i += 1024) {
        float v = p[i];
        mn = fminf(mn, v); mx = fmaxf(mx, v);
    }
    for (int off = 32; off; off >>= 1) {
        mn = fminf(mn, __shfl_down(mn, off));
        mx = fmaxf(mx, __shfl_down(mx, off));
    }
    __shared__ float smn[16], smx[16];
    int w = threadIdx.x >> 6;
    if ((threadIdx.x & 63) == 0) { smn[w] = mn; smx[w] = mx; }
    __syncthreads();
    if (threadIdx.x < 16) {
        mn = smn[threadIdx.x]; mx = smx[threadIdx.x];
        for (int off = 8; off; off >>= 1) {
            mn = fminf(mn, __shfl_down(mn, off));
            mx = fmaxf(mx, __shfl_down(mx, off));
        }
        if (threadIdx.x == 0) { mmf[2 * b] = mn; mmf[2 * b + 1] = mx; }
    }
}

__global__ __launch_bounds__(256) void das_norm(float* __restrict__ out,
                                                const float* __restrict__ mmf) {
    int i = blockIdx.x * 256 + threadIdx.x;
    int b = i >> 16;
    out[i] = __fdiv_rn(__fsub_rn(out[i], mmf[2 * b]), __fsub_rn(mmf[2 * b + 1], mmf[2 * b]));
}

extern "C" void kernel_launch(void* const* d_in, const int* in_sizes, int n_in,
                              void* d_out, int out_size, void* d_ws, size_t ws_size,
                              hipStream_t stream) {
    const float* data = (const float*)d_in[0];   // (B, S, T) fp32
    const int*   sxy  = (const int*)d_in[1];     // (S, 2) int32
    float* out = (float*)d_out;                  // (B, 256, 256) fp32

    if (ws_size >= WS_NEED) {
        float*    part = (float*)d_ws;
        unsigned* mm   = (unsigned*)((char*)d_ws + MM_OFF);
        das_accumw<<<NCHUNK * 256, 256, 0, stream>>>(data, sxy, part, mm);
        das_combine<<<(B * NPIX) / 1024, 256, 0, stream>>>(part, out, mm);
        das_norm3<<<(B * NPIX) / 1024, 256, 0, stream>>>(out, mm);
    } else {
        unsigned short* tab = (unsigned short*)d_ws;
        float* mmf = (float*)((char*)d_ws + NPIX * sizeof(unsigned short));
        build_tab<<<NPIX / 256, 256, 0, stream>>>(tab);
        das_accum<<<B * 256, 256, 0, stream>>>(data, sxy, tab, out);
        das_minmax<<<B, 1024, 0, stream>>>(out, mmf);
        das_norm<<<(B * NPIX) / 256, 256, 0, stream>>>(out, mmf);
    }
}

// Round 29
// 39.647 us; speedup vs baseline: 1.2119x; 1.2119x over previous
//
#include <hip/hip_runtime.h>
#include <math.h>

// Problem constants (match reference)
constexpr int B = 8, S = 128, T = 4096;
constexpr int NPIX = 256 * 256;          // NX*NY
constexpr float RVS = 1.0f / 1550.0f;    // compile-time correctly-rounded f32
constexpr float RDT = 1.0e7f;            // fl32(1/fl32(1e-7)) == 1e7 (exact)
constexpr int NCHUNK = 8;                // sensor chunks == XCD count
constexpr int SCHUNK = S / NCHUNK;       // 16
constexpr int WROWS  = 160;              // staged t-rows: span<=138 (+3 align) <160
constexpr size_t PART_BYTES = (size_t)NPIX * B * sizeof(float);       // 2 MB
constexpr size_t MM_OFF     = NCHUNK * PART_BYTES;                    // 16 MB
constexpr size_t WS_NEED    = MM_OFF + 256;

// Verified t-chain (round 11, absmax 0.0039): XLA f32 with x/const -> x*(1/const).
// Monotone non-decreasing in |dx|,|dy| (incl. rounding) -> interval endpoints
// give exact per-tile t-bounds.
__device__ __forceinline__ int tof_index(int dxi, int dyi) {
    float ax = (float)dxi * 1e-3f;
    float ay = (float)dyi * 1e-3f;
    float px = ax * ax;
    float py = ay * ay;
    asm volatile("" : "+v"(px));         // pin rounded squares: forbid FMA
    asm volatile("" : "+v"(py));
    float d2  = px + py;
    float dis = __fsqrt_rn(d2);
    float q1  = __fmul_rn(dis, RVS);
    asm volatile("" : "+v"(q1));
    float tf  = __fmul_rn(q1, RDT);
    return (int)tf;                      // t_max == 2326; 2326+159 < 4096 (in-bounds)
}

// Orderable uint mapping for float min/max atomics (monotonic, bijective).
__device__ __forceinline__ unsigned fkey(float f) {
    unsigned u = __float_as_uint(f);
    return ((int)u < 0) ? ~u : (u | 0x80000000u);
}
__device__ __forceinline__ float funkey(unsigned k) {
    return __uint_as_float(((int)k < 0) ? (k ^ 0x80000000u) : ~k);
}

// ---------- fast path (3 kernels) — round-21 form, best measured (39.7us) ----------

// Delay-and-sum with per-sensor LDS window staging from the original (B,S,T)
// layout. Per (block = 16x16 pixel tile, sensor): exact monotone t-window,
// staged as 320 float4 (8 batch-rows x 640B contiguous, coalesced,
// L2-resident: each XCD's 16-sensor slice is 2MB). Gathers are ds_read_b32
// from win[b][160]. (256,4): 64-VGPR budget, measured 28 VGPR, no spills.
// Block 0 initializes min/max keys (combine runs strictly after).
// Chunk k -> XCD k (bid&7). Six structural variants (occupancy tier, barrier
// grouping, double-buffer, t-hoist, NT stores) all measured neutral-to-
// negative vs this form (rounds 20-26).
__global__ __launch_bounds__(256, 4) void das_accumw(const float* __restrict__ data,
                                                     const int* __restrict__ sxy,
                                                     float* __restrict__ part,
                                                     unsigned* __restrict__ mm) {
    __shared__ float win[B * WROWS];              // 5120 B
    unsigned bid = blockIdx.x;
    int tid = threadIdx.x;
    if (bid == 0 && tid < 16) mm[tid] = (tid < 8) ? 0xFFFFFFFFu : 0u;

    int chunk = bid & 7;                          // -> XCD chunk
    int tile  = bid >> 3;                         // 0..255 (16x16 tile grid)
    int tx0 = ((tile >> 4) << 4), ty0 = ((tile & 15) << 4);
    int l = tid & 63, w = tid >> 6;
    int ix = tx0 + ((w >> 1) << 3) + (l >> 3);
    int iy = ty0 + ((w & 1) << 3) + (l & 7);
    int p  = (ix << 8) + iy;

    float acc[B];
#pragma unroll
    for (int b = 0; b < B; ++b) acc[b] = 0.0f;

    int s0 = chunk * SCHUNK;
    for (int k = 0; k < SCHUNK; ++k) {
        int s = s0 + k;
        int x = sxy[2 * s], y = sxy[2 * s + 1];   // uniform s_load
        // exact lower corner of the tile's t-window (uniform SALU)
        int dxi_min = max(0, max(tx0 - x, x - (tx0 + 15)));
        int dyi_min = max(0, max(ty0 - y, y - (ty0 + 15)));
        int tbase = tof_index(dxi_min, dyi_min) & ~3;   // float4-aligned

        __syncthreads();                          // win free of prev readers
        const float* srow = data + (size_t)s * T + tbase;
#pragma unroll
        for (int r = 0; r < 2; ++r) {
            int o4 = tid + r * 256;               // 0..319 (2nd round: 64 act.)
            if (o4 < (B * WROWS) / 4) {
                int b  = o4 / 40;                 // const divisor -> magic mul
                int t4 = o4 - b * 40;
                float4 v = *(const float4*)(srow + (size_t)b * (S * T) + t4 * 4);
                *(float4*)(&win[b * WROWS + t4 * 4]) = v;
            }
        }
        __syncthreads();                          // window visible

        int t = tof_index(abs(x - ix), abs(y - iy)) - tbase;  // in [0,160)
#pragma unroll
        for (int b = 0; b < B; ++b)
            acc[b] += win[b * WROWS + t];         // same add order as before
    }

    float* dst = part + (size_t)chunk * NPIX * B;
#pragma unroll
    for (int b = 0; b < B; ++b)
        __builtin_nontemporal_store(acc[b], dst + b * NPIX + p);
}

// Combine the 8 chunk partials into out AND per-batch min/max (atomic keys).
// 4 pixels/thread; each block spans 1024 consecutive pixels of ONE batch.
__global__ __launch_bounds__(256) void das_combine(const float* __restrict__ part,
                                                   float* __restrict__ out,
                                                   unsigned* __restrict__ mm) {
    size_t i4 = ((size_t)blockIdx.x * 256 + threadIdx.x) * 4;
    int b = (int)(i4 >> 16);
    float4 v = make_float4(0.f, 0.f, 0.f, 0.f);
#pragma unroll
    for (int c = 0; c < NCHUNK; ++c) {
        const float* q = part + (size_t)c * NPIX * B + i4;
        v.x += __builtin_nontemporal_load(q);
        v.y += __builtin_nontemporal_load(q + 1);
        v.z += __builtin_nontemporal_load(q + 2);
        v.w += __builtin_nontemporal_load(q + 3);
    }
    *(float4*)(out + i4) = v;

    float mn = fminf(fminf(v.x, v.y), fminf(v.z, v.w));
    float mx = fmaxf(fmaxf(v.x, v.y), fmaxf(v.z, v.w));
    for (int off = 32; off; off >>= 1) {
        mn = fminf(mn, __shfl_down(mn, off));
        mx = fmaxf(mx, __shfl_down(mx, off));
    }
    __shared__ float smn[4], smx[4];
    int w = threadIdx.x >> 6;
    if ((threadIdx.x & 63) == 0) { smn[w] = mn; smx[w] = mx; }
    __syncthreads();
    if (threadIdx.x == 0) {
        mn = fminf(fminf(smn[0], smn[1]), fminf(smn[2], smn[3]));
        mx = fmaxf(fmaxf(smx[0], smx[1]), fmaxf(smx[2], smx[3]));
        atomicMin(&mm[b], fkey(mn));
        atomicMax(&mm[8 + b], fkey(mx));
    }
}

// Per-batch min-max normalization, 4 pixels/thread, in place.
__global__ __launch_bounds__(256) void das_norm3(float* __restrict__ out,
                                                 const unsigned* __restrict__ mm) {
    size_t i4 = ((size_t)blockIdx.x * 256 + threadIdx.x) * 4;
    int b = (int)(i4 >> 16);
    float mn = funkey(mm[b]);
    float rs = __fsub_rn(funkey(mm[8 + b]), mn);
    float4 v = *(float4*)(out + i4);
    v.x = __fdiv_rn(__fsub_rn(v.x, mn), rs);
    v.y = __fdiv_rn(__fsub_rn(v.y, mn), rs);
    v.z = __fdiv_rn(__fsub_rn(v.z, mn), rs);
    v.w = __fdiv_rn(__fsub_rn(v.w, mn), rs);
    *(float4*)(out + i4) = v;
}

// ---------- fallback path (round-12, proven, needs 128KB ws) ----------

__global__ __launch_bounds__(256) void build_tab(unsigned short* __restrict__ tab) {
    int i = blockIdx.x * 256 + threadIdx.x;
    tab[i] = (unsigned short)tof_index(i >> 8, i & 255);
}

__global__ __launch_bounds__(256) void das_accum(const float* __restrict__ data,
                                                 const int* __restrict__ sxy,
                                                 const unsigned short* __restrict__ tab,
                                                 float* __restrict__ out) {
    __shared__ int sx[S], sy[S];
    int tid = threadIdx.x;
    if (tid < S) { sx[tid] = sxy[2 * tid]; sy[tid] = sxy[2 * tid + 1]; }
    __syncthreads();
    int b = blockIdx.x >> 8, ix = blockIdx.x & 255, iy = tid;
    int p = (ix << 8) + iy;
    const float* dbase = data + b * (S * T);
    double acc = 0.0;
#pragma unroll 8
    for (int s = 0; s < S; ++s) {
        int t = (int)tab[(abs(sx[s] - ix) << 8) + abs(sy[s] - iy)];
        acc += (double)dbase[s * T + t];
    }
    out[b * NPIX + p] = (float)acc;
}

__global__ __launch_bounds__(1024) void das_minmax(const float* __restrict__ img,
                                                   float* __restrict__ mmf) {
    int b = blockIdx.x;
    const float* p = img + b * NPIX;
    float mn = 3.0e38f, mx = -3.0e38f;
    for (int i = threadIdx.x; i < NPIX; i += 1024) {
        float v = p[i];
        mn = fminf(mn, v); mx = fmaxf(mx, v);
    }
    for (int off = 32; off; off >>= 1) {
        mn = fminf(mn, __shfl_down(mn, off));
        mx = fmaxf(mx, __shfl_down(mx, off));
    }
    __shared__ float smn[16], smx[16];
    int w = threadIdx.x >> 6;
    if ((threadIdx.x & 63) == 0) { smn[w] = mn; smx[w] = mx; }
    __syncthreads();
    if (threadIdx.x < 16) {
        mn = smn[threadIdx.x]; mx = smx[threadIdx.x];
        for (int off = 8; off; off >>= 1) {
            mn = fminf(mn, __shfl_down(mn, off));
            mx = fmaxf(mx, __shfl_down(mx, off));
        }
        if (threadIdx.x == 0) { mmf[2 * b] = mn; mmf[2 * b + 1] = mx; }
    }
}

__global__ __launch_bounds__(256) void das_norm(float* __restrict__ out,
                                                const float* __restrict__ mmf) {
    int i = blockIdx.x * 256 + threadIdx.x;
    int b = i >> 16;
    out[i] = __fdiv_rn(__fsub_rn(out[i], mmf[2 * b]), __fsub_rn(mmf[2 * b + 1], mmf[2 * b]));
}

extern "C" void kernel_launch(void* const* d_in, const int* in_sizes, int n_in,
                              void* d_out, int out_size, void* d_ws, size_t ws_size,
                              hipStream_t stream) {
    const float* data = (const float*)d_in[0];   // (B, S, T) fp32
    const int*   sxy  = (const int*)d_in[1];     // (S, 2) int32
    float* out = (float*)d_out;                  // (B, 256, 256) fp32

    if (ws_size >= WS_NEED) {
        float*    part = (float*)d_ws;
        unsigned* mm   = (unsigned*)((char*)d_ws + MM_OFF);
        das_accumw<<<NCHUNK * 256, 256, 0, stream>>>(data, sxy, part, mm);
        das_combine<<<(B * NPIX) / 1024, 256, 0, stream>>>(part, out, mm);
        das_norm3<<<(B * NPIX) / 1024, 256, 0, stream>>>(out, mm);
    } else {
        unsigned short* tab = (unsigned short*)d_ws;
        float* mmf = (float*)((char*)d_ws + NPIX * sizeof(unsigned short));
        build_tab<<<NPIX / 256, 256, 0, stream>>>(tab);
        das_accum<<<B * 256, 256, 0, stream>>>(data, sxy, tab, out);
        das_minmax<<<B, 1024, 0, stream>>>(out, mmf);
        das_norm<<<(B * NPIX) / 256, 256, 0, stream>>>(out, mmf);
    }
}